// Round 1
// 503.311 us; speedup vs baseline: 1.1257x; 1.1257x over previous
//
#include <hip/hip_runtime.h>

// FastMaskedDense1D.update_site  — skinny GEMM  y = A @ K + bias[index]
//   A: (8192 batch, 4800 k)  from cache[:, :299, :] with row 299 <- inputs
//   K: (4800, 16)            strided slice of kernel (row stride 8192 floats)
// Memory-bound: 157 MB A-read @ 6.3 TB/s => ~25 us floor.
//
// R1: K loads had a 32 KB power-of-2 stride -> 4800 lines collapse into ~8 L2
// set-groups -> permanent L2 thrash, ~300 MB/dispatch of scattered L3 traffic
// (the real 200 us). Pre-pack K into a contiguous (jc*16, 16) buffer in d_ws;
// the main kernel then reads a dense, L2-resident 307 KB array.

#define EXCLUSIVE 1
#define SIZEV     512
#define NF        16
#define NIF       16
#define KROW      (SIZEV * NF)    // kernel row stride in floats (8192)
#define CROW      (SIZEV * NIF)   // cache per-batch stride in floats (8192)
#define MB        16              // batch rows per block
#define KC        256             // k-values per LDS chunk
#define SA        272             // LDS row stride (words): bank = 16*rq + kq -> 2-way max (free)

__device__ __forceinline__ void fma4(float4& a, float s, float4 b) {
    a.x = fmaf(s, b.x, a.x);
    a.y = fmaf(s, b.y, a.y);
    a.z = fmaf(s, b.z, a.z);
    a.w = fmaf(s, b.w, a.w);
}

__device__ __forceinline__ float4 red4(float4 v, int m) {
    v.x += __shfl_xor(v.x, m, 64);
    v.y += __shfl_xor(v.y, m, 64);
    v.z += __shfl_xor(v.z, m, 64);
    v.w += __shfl_xor(v.w, m, 64);
    return v;
}

// Gather the used K slice into a dense (rows, 16) buffer.
// rows = jc*16 (<= 8192). 4 threads per row, one float4 each.
__global__ __launch_bounds__(256) void pack_k(
    const float* __restrict__ kern,
    const int*   __restrict__ idxp,
    float*       __restrict__ kp)
{
    const int index = *idxp;
    const int jc = index - EXCLUSIVE + 1;
    const int KT = (jc > 0) ? jc * NIF : 0;       // packed rows (4800 for index=300)
    const int t  = blockIdx.x * blockDim.x + threadIdx.x;
    const int r  = t >> 2;                        // k-row
    const int q  = t & 3;                         // float4 within the 16-float row
    if (r < KT) {
        const float4 v = *(const float4*)(kern + (size_t)r * KROW + (size_t)index * NF + 4 * q);
        *(float4*)(kp + (size_t)r * NF + 4 * q) = v;
    }
}

__global__ __launch_bounds__(256) void fmd_kernel(
    const float* __restrict__ inputs,   // (B, 16)
    const float* __restrict__ cache,    // (B, 512, 16)
    const float* __restrict__ kp,       // packed K: (jc*16, 16) in workspace
    const float* __restrict__ bias,     // (512, 16)
    const int*   __restrict__ idxp,     // scalar
    float*       __restrict__ out)      // (B, 16)
{
    __shared__ float A[2][MB * SA];     // double-buffered A tile, ~34.8 KB

    const int index = *idxp;
    const int jc = index - EXCLUSIVE + 1;        // valid sites; last one sourced from `inputs`
    const int KM = (jc > 0) ? (jc - 1) * NIF : 0; // cache-sourced flattened-k count (mult of 16)
    const int NC = (KM + KC - 1) / KC;           // number of k-chunks

    const int tid  = threadIdx.x;
    const int lane = tid & 63;
    const int w    = tid >> 6;      // wave 0..3
    const int kq   = lane & 15;     // k-slice within chunk
    const int rq   = lane >> 4;     // row group 0..3
    const int rh   = w >> 1;        // row half
    const int fh   = w & 1;         // feature half (8 features)
    const int row0 = blockIdx.x * MB;

    const int lr0 = rh * 8 + rq;    // lane's block-local rows
    const int lr1 = lr0 + 4;

    float4 acc00 = {0,0,0,0}, acc01 = {0,0,0,0};
    float4 acc10 = {0,0,0,0}, acc11 = {0,0,0,0};

    const float4* cvec  = (const float4*)cache;
    const float*  kbase = kp + (size_t)fh * 8;   // dense rows of 16 floats

    float4 st[4];  // staged A for next chunk (thread stages rows w, w+4, w+8, w+12)

    if (NC > 0) {
        // ---- prolog: stage chunk 0 into buf 0 ----
        #pragma unroll
        for (int p = 0; p < 4; ++p)
            st[p] = cvec[(size_t)(row0 + w + 4*p) * (CROW/4) + lane];
        #pragma unroll
        for (int p = 0; p < 4; ++p)
            *(float4*)&A[0][(w + 4*p) * SA + lane * 4] = st[p];

        for (int c = 0; c < NC; ++c) {
            const int k0 = c * KC;
            // fire next chunk's global loads (fully in-bounds: k0+KC+1023B < row end)
            if (c + 1 < NC) {
                const int k4 = (k0 + KC) >> 2;
                #pragma unroll
                for (int p = 0; p < 4; ++p)
                    st[p] = cvec[(size_t)(row0 + w + 4*p) * (CROW/4) + k4 + lane];
            }
            __syncthreads();   // prev ds_writes visible; separates readers from upcoming writes

            const int buf  = c & 1;
            const int kend = min(KC, KM - k0);   // multiple of 16
            const int nt   = kend >> 4;
            const float* Ab = &A[buf][0];

            #pragma unroll 4
            for (int t = 0; t < nt; ++t) {
                const int kk = kq + 16 * t;
                float a0 = Ab[lr0 * SA + kk];
                float a1 = Ab[lr1 * SA + kk];
                const float* kptr = kbase + (size_t)(k0 + kk) * NF;   // dense, L2-resident
                float4 kv0 = *(const float4*)kptr;
                float4 kv1 = *(const float4*)(kptr + 4);
                fma4(acc00, a0, kv0); fma4(acc01, a0, kv1);
                fma4(acc10, a1, kv0); fma4(acc11, a1, kv1);
            }

            if (c + 1 < NC) {
                const int b2 = (c + 1) & 1;
                #pragma unroll
                for (int p = 0; p < 4; ++p)
                    *(float4*)&A[b2][(w + 4*p) * SA + lane * 4] = st[p];
            }
        }
    }

    // ---- epilogue: row j = jc-1 comes from `inputs` (the scattered site) ----
    if (jc > 0) {
        const float* kptr = kbase + (size_t)((jc - 1) * NIF + kq) * NF;
        float4 kv0 = *(const float4*)kptr;
        float4 kv1 = *(const float4*)(kptr + 4);
        float in0 = inputs[(size_t)(row0 + lr0) * NIF + kq];
        float in1 = inputs[(size_t)(row0 + lr1) * NIF + kq];
        fma4(acc00, in0, kv0); fma4(acc01, in0, kv1);
        fma4(acc10, in1, kv0); fma4(acc11, in1, kv1);
    }

    // ---- butterfly reduce over the 16 kq lanes (xor bits 0..3) ----
    #pragma unroll
    for (int m = 1; m <= 8; m <<= 1) {
        acc00 = red4(acc00, m); acc01 = red4(acc01, m);
        acc10 = red4(acc10, m); acc11 = red4(acc11, m);
    }

    // ---- write: lanes kq<4 each store one float4 (+bias) ----
    if (kq < 4) {
        const int rp = kq >> 1;   // which of the lane's two rows
        const int qp = kq & 1;    // which feature quad within the half
        float4 v = (rp == 0) ? (qp == 0 ? acc00 : acc01)
                             : (qp == 0 ? acc10 : acc11);
        const int row  = row0 + lr0 + 4 * rp;
        const int fcol = fh * 8 + qp * 4;
        float4 b4 = *(const float4*)&bias[(size_t)index * NF + fcol];
        v.x += b4.x; v.y += b4.y; v.z += b4.z; v.w += b4.w;
        *(float4*)&out[(size_t)row * NF + fcol] = v;
    }
}

extern "C" void kernel_launch(void* const* d_in, const int* in_sizes, int n_in,
                              void* d_out, int out_size, void* d_ws, size_t ws_size,
                              hipStream_t stream) {
    const float* inputs = (const float*)d_in[0];
    const float* cache  = (const float*)d_in[1];
    const float* kern   = (const float*)d_in[2];
    const float* bias   = (const float*)d_in[3];
    const int*   idxp   = (const int*)d_in[4];
    float*       out    = (float*)d_out;
    float*       kp     = (float*)d_ws;          // packed K, max 512*16*16*4 = 512 KB

    const int batch = in_sizes[0] / NIF;         // 8192
    const int grid  = batch / MB;                // 512 blocks (2/CU)

    // max packed rows = SIZEV*NIF = 8192; 4 threads/row
    pack_k<<<(SIZEV * NIF * 4) / 256, 256, 0, stream>>>(kern, idxp, kp);
    fmd_kernel<<<grid, 256, 0, stream>>>(inputs, cache, kp, bias, idxp, out);
}

// Round 2
// 438.068 us; speedup vs baseline: 1.2934x; 1.1489x over previous
//
#include <hip/hip_runtime.h>

// FastMaskedDense1D.update_site  — skinny GEMM  y = A @ K + bias[index]
//   A: (8192 batch, 4800 k)  from cache[:, :299, :] with row 299 <- inputs
//   K: (4800, 16)            strided slice of kernel (row stride 8192 floats)
// Memory-bound: 157 MB A-read @ 6.3 TB/s => ~25 us floor.
//
// R1: packed K into contiguous ws buffer (killed the 32KB-stride L2 set-thrash).
// R2: inner-loop K loads were still a 16-addr x 16B scatter through an L1 that
// the A-stream constantly evicts, at 25% occupancy -> latency-bound (~135 us).
// Now: K chunk lives in LDS (double-buffered, coalesced staging from kp,
// row stride 20 words = conflict-free b128 reads), 512-thread blocks with a
// 2-way wave k-split -> 16 waves/CU. Inner loop is pure LDS+FMA.

#define EXCLUSIVE 1
#define SIZEV     512
#define NF        16
#define NIF       16
#define KROW      (SIZEV * NF)    // kernel row stride in floats (8192)
#define CROW      (SIZEV * NIF)   // cache per-batch stride in floats (8192)
#define MB        16              // batch rows per block
#define KC        128             // k-values per LDS chunk
#define SA        136             // A LDS row stride (words): bank = 8*lr + kq -> 2-way max (free)
#define SK        20              // K LDS row stride (words): 20*kq%32 tiles quads 2-way (free)

__device__ __forceinline__ void fma4(float4& a, float s, float4 b) {
    a.x = fmaf(s, b.x, a.x);
    a.y = fmaf(s, b.y, a.y);
    a.z = fmaf(s, b.z, a.z);
    a.w = fmaf(s, b.w, a.w);
}

__device__ __forceinline__ float4 red4(float4 v, int m) {
    v.x += __shfl_xor(v.x, m, 64);
    v.y += __shfl_xor(v.y, m, 64);
    v.z += __shfl_xor(v.z, m, 64);
    v.w += __shfl_xor(v.w, m, 64);
    return v;
}

// Gather the used K slice into a dense (rows, 16) buffer; zero-pad to the KC
// boundary so fmd's over-staging of the last chunk never reads poison.
__global__ __launch_bounds__(256) void pack_k(
    const float* __restrict__ kern,
    const int*   __restrict__ idxp,
    float*       __restrict__ kp)
{
    const int index = *idxp;
    const int jc = index - EXCLUSIVE + 1;
    const int KT = (jc > 0) ? jc * NIF : 0;          // valid packed rows (4800)
    const int KTpad = (KT + KC - 1) & ~(KC - 1);     // staged reach (4864)
    const int t  = blockIdx.x * blockDim.x + threadIdx.x;
    const int r  = t >> 2;                           // k-row
    const int q  = t & 3;                            // float4 within the row
    if (r < KTpad) {
        float4 v = {0.f, 0.f, 0.f, 0.f};
        if (r < KT)
            v = *(const float4*)(kern + (size_t)r * KROW + (size_t)index * NF + 4 * q);
        *(float4*)(kp + (size_t)r * NF + 4 * q) = v;
    }
}

__global__ __launch_bounds__(512) void fmd_kernel(
    const float* __restrict__ inputs,   // (B, 16)
    const float* __restrict__ cache,    // (B, 512, 16)
    const float* __restrict__ kp,       // packed K: (KTpad, 16) in workspace
    const float* __restrict__ bias,     // (512, 16)
    const int*   __restrict__ idxp,     // scalar
    float*       __restrict__ out)      // (B, 16)
{
    __shared__ float A [2][MB * SA];    // 17.4 KB
    __shared__ float Kl[2][KC * SK];    // 20.5 KB
    __shared__ float Red[MB * NF];      // 1 KB  (ks-pair combine)

    const int index = *idxp;
    const int jc = index - EXCLUSIVE + 1;
    const int KM = (jc > 0) ? (jc - 1) * NIF : 0;   // cache-sourced k count (mult of 16)
    const int NC = (KM + KC - 1) / KC;

    const int tid  = threadIdx.x;
    const int lane = tid & 63;
    const int w    = tid >> 6;      // wave 0..7
    const int kq   = lane & 15;     // k-slice within 16
    const int rq   = lane >> 4;     // row group 0..3
    const int fh   = w & 1;         // feature half
    const int rh   = (w >> 1) & 1;  // row half
    const int ks   = w >> 2;        // k sub-split 0..1
    const int row0 = blockIdx.x * MB;

    const int lr0 = rh * 8 + rq;    // lane's block-local rows
    const int lr1 = lr0 + 4;

    // staging maps (one float4 of A and one of K per thread per chunk)
    const int arow = tid >> 5;            // 0..15
    const int ac4  = tid & 31;            // float4 col 0..31
    const int krow = tid >> 2;            // 0..127
    const int kc4  = tid & 3;             // float4 col 0..3

    float4 acc00 = {0,0,0,0}, acc01 = {0,0,0,0};
    float4 acc10 = {0,0,0,0}, acc11 = {0,0,0,0};

    const float4* cvec = (const float4*)cache;
    const float4* kpv  = (const float4*)kp;

    float4 stA, stK;

    if (NC > 0) {
        // ---- prolog: stage chunk 0 into buf 0 ----
        stA = cvec[(size_t)(row0 + arow) * (CROW/4) + ac4];
        stK = kpv[4 * krow + kc4];
        *(float4*)&A [0][arow * SA + 4 * ac4] = stA;
        *(float4*)&Kl[0][krow * SK + 4 * kc4] = stK;

        for (int c = 0; c < NC; ++c) {
            const int k0 = c * KC;
            // fire next chunk's global loads (A over-read stays inside the row;
            // K over-read stays inside the zero-padded KTpad region)
            if (c + 1 < NC) {
                stA = cvec[(size_t)(row0 + arow) * (CROW/4) + ((k0 + KC) >> 2) + ac4];
                stK = kpv[4 * (k0 + KC + krow) + kc4];
            }
            __syncthreads();   // prev ds_writes visible; separates readers from upcoming writes

            const int buf  = c & 1;
            const int kend = min(KC, KM - k0);          // multiple of 16
            const int nt   = (kend - 16 * ks + 31) >> 5; // this wave's t-iters
            const float* Ab = &A [buf][0];
            const float* Kb = &Kl[buf][0];

            #pragma unroll 4
            for (int t = 0; t < nt; ++t) {
                const int kk = kq + 32 * t + 16 * ks;
                float a0 = Ab[lr0 * SA + kk];
                float a1 = Ab[lr1 * SA + kk];
                const float* kp4 = &Kb[kk * SK + fh * 8];   // 16B-aligned (80*kk bytes)
                float4 kv0 = *(const float4*)kp4;
                float4 kv1 = *(const float4*)(kp4 + 4);
                fma4(acc00, a0, kv0); fma4(acc01, a0, kv1);
                fma4(acc10, a1, kv0); fma4(acc11, a1, kv1);
            }

            if (c + 1 < NC) {
                const int b2 = (c + 1) & 1;
                *(float4*)&A [b2][arow * SA + 4 * ac4] = stA;
                *(float4*)&Kl[b2][krow * SK + 4 * kc4] = stK;
            }
        }
    }

    // ---- epilogue: row j = jc-1 comes from `inputs` (only ks==0 waves!) ----
    if (jc > 0 && ks == 0) {
        const float* kg = kp + (size_t)((jc - 1) * NIF + kq) * NF + fh * 8;
        float4 kv0 = *(const float4*)kg;
        float4 kv1 = *(const float4*)(kg + 4);
        float in0 = inputs[(size_t)(row0 + lr0) * NIF + kq];
        float in1 = inputs[(size_t)(row0 + lr1) * NIF + kq];
        fma4(acc00, in0, kv0); fma4(acc01, in0, kv1);
        fma4(acc10, in1, kv0); fma4(acc11, in1, kv1);
    }

    // ---- butterfly reduce over the 16 kq lanes ----
    #pragma unroll
    for (int m = 1; m <= 8; m <<= 1) {
        acc00 = red4(acc00, m); acc01 = red4(acc01, m);
        acc10 = red4(acc10, m); acc10 = acc10; acc11 = red4(acc11, m);
    }

    // ---- combine the two ks halves via LDS, then write (+bias) ----
    const int rp = kq >> 1;   // which of the lane's two rows
    const int qp = kq & 1;    // which feature quad within the half
    float4 v = (rp == 0) ? (qp == 0 ? acc00 : acc01)
                         : (qp == 0 ? acc10 : acc11);
    const int brow = lr0 + 4 * rp;          // block-local row 0..15
    const int fcol = fh * 8 + 4 * qp;       // feature col {0,4,8,12}

    if (ks == 1 && kq < 4)
        *(float4*)&Red[brow * NF + fcol] = v;
    __syncthreads();
    if (ks == 0 && kq < 4) {
        float4 o  = *(const float4*)&Red[brow * NF + fcol];
        float4 b4 = *(const float4*)&bias[(size_t)index * NF + fcol];
        v.x += o.x + b4.x; v.y += o.y + b4.y;
        v.z += o.z + b4.z; v.w += o.w + b4.w;
        *(float4*)&out[(size_t)(row0 + brow) * NF + fcol] = v;
    }
}

extern "C" void kernel_launch(void* const* d_in, const int* in_sizes, int n_in,
                              void* d_out, int out_size, void* d_ws, size_t ws_size,
                              hipStream_t stream) {
    const float* inputs = (const float*)d_in[0];
    const float* cache  = (const float*)d_in[1];
    const float* kern   = (const float*)d_in[2];
    const float* bias   = (const float*)d_in[3];
    const int*   idxp   = (const int*)d_in[4];
    float*       out    = (float*)d_out;
    float*       kp     = (float*)d_ws;          // packed K, max 8192*16*4 = 512 KB

    const int batch = in_sizes[0] / NIF;         // 8192
    const int grid  = batch / MB;                // 512 blocks (2/CU, 16 waves/CU)

    pack_k<<<(SIZEV * NIF * 4) / 256, 256, 0, stream>>>(kern, idxp, kp);
    fmd_kernel<<<grid, 512, 0, stream>>>(inputs, cache, kp, bias, idxp, out);
}